// Round 1
// baseline (321.404 us; speedup 1.0000x reference)
//
#include <hip/hip_runtime.h>
#include <math.h>

#define N_ATOMS  50000
#define N_NBRS   32
#define N_BASIS  128
#define N_FILT   128
#define N_GAUSS  25
#define RCUT     5.0f
#define T_TAB    2048
#define AM       8     // atoms per block in main kernel
#define YM       8     // atoms per block in y kernel
#define PI_F     3.14159265358979323846f

// shifted softplus: log(1+e^x) - log(2), numerically stable
__device__ __forceinline__ float ssp(float x) {
  return fmaxf(x, 0.0f) + log1pf(__expf(-fabsf(x))) - 0.69314718055994531f;
}

// Build W(r)*fcut(r) lookup table: one block per table entry, thread = channel f.
__global__ void build_table_kernel(const float* __restrict__ fw1,
                                   const float* __restrict__ fb1,
                                   const float* __restrict__ fw2,
                                   const float* __restrict__ fb2,
                                   float* __restrict__ table,
                                   float* __restrict__ out) {
  const int i = blockIdx.x;
  const int f = threadIdx.x;
  if (i == 0 && f == 0) out[0] = 0.0f;   // zero the scalar accumulator (d_out is poisoned)
  const float r = (float)i * (RCUT / (float)(T_TAB - 1));
  const float delta = RCUT / (float)(N_GAUSS - 1);
  const float coeff = -0.5f / (delta * delta);
  float h = fb1[f];
  #pragma unroll
  for (int g = 0; g < N_GAUSS; ++g) {
    const float d = r - (float)g * delta;
    h = fmaf(__expf(coeff * d * d), fw1[g * N_FILT + f], h);
  }
  h = ssp(h);
  __shared__ float hl[N_FILT];
  hl[f] = h;
  __syncthreads();
  float w = fb2[f];
  for (int j = 0; j < N_FILT; j += 4) {
    const float4 hv = *reinterpret_cast<const float4*>(&hl[j]);
    w = fmaf(hv.x, fw2[(j + 0) * N_FILT + f], w);
    w = fmaf(hv.y, fw2[(j + 1) * N_FILT + f], w);
    w = fmaf(hv.z, fw2[(j + 2) * N_FILT + f], w);
    w = fmaf(hv.w, fw2[(j + 3) * N_FILT + f], w);
  }
  const float fc = (r < RCUT) ? 0.5f * (__cosf(r * PI_F / RCUT) + 1.0f) : 0.0f;
  table[i * N_FILT + f] = w * fc;
}

// y = embed[Z] @ in2f_w, [N, 128] -> workspace
__global__ void compute_y_kernel(const int* __restrict__ Z,
                                 const float* __restrict__ embed,
                                 const float* __restrict__ in2f,
                                 float* __restrict__ y) {
  const int f = threadIdx.x;
  const int a0 = blockIdx.x * YM;
  __shared__ float xs[YM][N_BASIS];
  #pragma unroll
  for (int m = 0; m < YM; ++m) {
    xs[m][f] = embed[Z[a0 + m] * N_BASIS + f];
  }
  __syncthreads();
  float acc[YM];
  #pragma unroll
  for (int m = 0; m < YM; ++m) acc[m] = 0.0f;
  for (int i = 0; i < N_BASIS; i += 4) {
    const float w0 = in2f[(i + 0) * N_FILT + f];
    const float w1 = in2f[(i + 1) * N_FILT + f];
    const float w2 = in2f[(i + 2) * N_FILT + f];
    const float w3 = in2f[(i + 3) * N_FILT + f];
    #pragma unroll
    for (int m = 0; m < YM; ++m) {
      const float4 xv = *reinterpret_cast<const float4*>(&xs[m][i]);
      acc[m] = fmaf(xv.x, w0, acc[m]);
      acc[m] = fmaf(xv.y, w1, acc[m]);
      acc[m] = fmaf(xv.z, w2, acc[m]);
      acc[m] = fmaf(xv.w, w3, acc[m]);
    }
  }
  #pragma unroll
  for (int m = 0; m < YM; ++m) y[(size_t)(a0 + m) * N_FILT + f] = acc[m];
}

// Fused: cfconv (table-lerp filter) + f2out + residual + atomwise MLP + sum
__global__ void __launch_bounds__(128)
schnet_main_kernel(const float* __restrict__ dR,
                   const int* __restrict__ Z,
                   const int* __restrict__ nbr,
                   const float* __restrict__ embed,
                   const float* __restrict__ table,
                   const float* __restrict__ y,
                   const float* __restrict__ w1, const float* __restrict__ b1,
                   const float* __restrict__ w2, const float* __restrict__ b2,
                   const float* __restrict__ mw1, const float* __restrict__ mb1,
                   const float* __restrict__ mw2, const float* __restrict__ mb2,
                   float* __restrict__ out) {
  const int f = threadIdx.x;
  const int a0 = blockIdx.x * AM;
  __shared__ float sA[AM][N_FILT];
  __shared__ float sB[AM][N_FILT];
  __shared__ float sdR[AM][N_NBRS];
  __shared__ int   snbr[AM][N_NBRS];

  for (int t = f; t < AM * N_NBRS; t += 128) {
    const int m = t >> 5, k = t & 31;
    sdR[m][k]  = dR[(a0 + m) * N_NBRS + k];
    snbr[m][k] = nbr[(a0 + m) * N_NBRS + k];
  }
  __syncthreads();

  // ---- cfconv: agg[m][f] = sum_k y[nbr][f] * W(dR)[f] ----
  float agg[AM];
  #pragma unroll
  for (int m = 0; m < AM; ++m) agg[m] = 0.0f;
  const float scale = (float)(T_TAB - 1) / RCUT;
  for (int k = 0; k < N_NBRS; ++k) {
    #pragma unroll
    for (int m = 0; m < AM; ++m) {
      const float r = sdR[m][k];
      const float u = r * scale;
      int i0 = (int)u;
      i0 = min(i0, T_TAB - 2);
      const float fr = u - (float)i0;
      const int nb = snbr[m][k];
      const float wl = table[i0 * N_FILT + f];
      const float wh = table[(i0 + 1) * N_FILT + f];
      const float wv = fmaf(fr, wh - wl, wl);
      agg[m] = fmaf(y[(size_t)nb * N_FILT + f], wv, agg[m]);
    }
  }

  #pragma unroll
  for (int m = 0; m < AM; ++m) sA[m][f] = agg[m];
  __syncthreads();

  // ---- f2out layer 1: h1 = ssp(agg @ w1 + b1) ----
  float h1[AM];
  #pragma unroll
  for (int m = 0; m < AM; ++m) h1[m] = b1[f];
  for (int i = 0; i < N_FILT; i += 4) {
    const float c0 = w1[(i + 0) * N_FILT + f];
    const float c1 = w1[(i + 1) * N_FILT + f];
    const float c2 = w1[(i + 2) * N_FILT + f];
    const float c3 = w1[(i + 3) * N_FILT + f];
    #pragma unroll
    for (int m = 0; m < AM; ++m) {
      const float4 av = *reinterpret_cast<const float4*>(&sA[m][i]);
      h1[m] = fmaf(av.x, c0, h1[m]);
      h1[m] = fmaf(av.y, c1, h1[m]);
      h1[m] = fmaf(av.z, c2, h1[m]);
      h1[m] = fmaf(av.w, c3, h1[m]);
    }
  }
  #pragma unroll
  for (int m = 0; m < AM; ++m) sB[m][f] = ssp(h1[m]);
  __syncthreads();

  // ---- f2out layer 2: v = h1s @ w2 + b2; xnew = embed[Z] + v ----
  float v[AM];
  #pragma unroll
  for (int m = 0; m < AM; ++m) v[m] = b2[f];
  for (int i = 0; i < N_FILT; i += 4) {
    const float c0 = w2[(i + 0) * N_FILT + f];
    const float c1 = w2[(i + 1) * N_FILT + f];
    const float c2 = w2[(i + 2) * N_FILT + f];
    const float c3 = w2[(i + 3) * N_FILT + f];
    #pragma unroll
    for (int m = 0; m < AM; ++m) {
      const float4 bv = *reinterpret_cast<const float4*>(&sB[m][i]);
      v[m] = fmaf(bv.x, c0, v[m]);
      v[m] = fmaf(bv.y, c1, v[m]);
      v[m] = fmaf(bv.z, c2, v[m]);
      v[m] = fmaf(bv.w, c3, v[m]);
    }
  }
  #pragma unroll
  for (int m = 0; m < AM; ++m) {
    const int z = Z[a0 + m];
    sA[m][f] = embed[z * N_BASIS + f] + v[m];   // residual
  }
  __syncthreads();   // sB reads done, sA(xnew) written

  // ---- MLP layer 1: 128 -> 64, split input halves across thread halves ----
  const int j = f & 63;
  const int base = (f >> 6) * 64;
  float p[AM];
  #pragma unroll
  for (int m = 0; m < AM; ++m) p[m] = 0.0f;
  for (int i = 0; i < 64; i += 4) {
    const float c0 = mw1[(base + i + 0) * 64 + j];
    const float c1 = mw1[(base + i + 1) * 64 + j];
    const float c2 = mw1[(base + i + 2) * 64 + j];
    const float c3 = mw1[(base + i + 3) * 64 + j];
    #pragma unroll
    for (int m = 0; m < AM; ++m) {
      const float4 av = *reinterpret_cast<const float4*>(&sA[m][base + i]);
      p[m] = fmaf(av.x, c0, p[m]);
      p[m] = fmaf(av.y, c1, p[m]);
      p[m] = fmaf(av.z, c2, p[m]);
      p[m] = fmaf(av.w, c3, p[m]);
    }
  }
  #pragma unroll
  for (int m = 0; m < AM; ++m) sB[m][f] = p[m];
  __syncthreads();

  // ---- MLP layer 2 (64 -> 1) + scale + block-sum + atomic ----
  if (f < 64) {
    float s = 0.0f;
    const float c = mw2[f];
    #pragma unroll
    for (int m = 0; m < AM; ++m) {
      const float hm = ssp(sB[m][f] + sB[m][f + 64] + mb1[f]);
      s = fmaf(hm, c, s);
    }
    #pragma unroll
    for (int o = 32; o > 0; o >>= 1) s += __shfl_xor(s, o, 64);
    if (f == 0) {
      const float total = 20.0f * (s + (float)AM * mb2[0]);  // STDDEV=20, MEAN=0
      atomicAdd(out, total);
    }
  }
}

extern "C" void kernel_launch(void* const* d_in, const int* in_sizes, int n_in,
                              void* d_out, int out_size, void* d_ws, size_t ws_size,
                              hipStream_t stream) {
  const float* dR    = (const float*)d_in[0];
  const int*   Z     = (const int*)  d_in[1];
  const int*   nbr   = (const int*)  d_in[2];
  const float* embed = (const float*)d_in[3];
  const float* fw1   = (const float*)d_in[4];
  const float* fb1   = (const float*)d_in[5];
  const float* fw2   = (const float*)d_in[6];
  const float* fb2   = (const float*)d_in[7];
  const float* in2f  = (const float*)d_in[8];
  const float* w1    = (const float*)d_in[9];
  const float* b1    = (const float*)d_in[10];
  const float* w2    = (const float*)d_in[11];
  const float* b2    = (const float*)d_in[12];
  const float* mw1   = (const float*)d_in[13];
  const float* mb1   = (const float*)d_in[14];
  const float* mw2   = (const float*)d_in[15];
  const float* mb2   = (const float*)d_in[16];
  float* out = (float*)d_out;

  float* y     = (float*)d_ws;                     // 50000*128 f32 = 25.6 MB
  float* table = y + (size_t)N_ATOMS * N_FILT;     // 2048*128 f32 = 1 MB

  build_table_kernel<<<T_TAB, 128, 0, stream>>>(fw1, fb1, fw2, fb2, table, out);
  compute_y_kernel<<<N_ATOMS / YM, 128, 0, stream>>>(Z, embed, in2f, y);
  schnet_main_kernel<<<N_ATOMS / AM, 128, 0, stream>>>(dR, Z, nbr, embed, table, y,
      w1, b1, w2, b2, mw1, mb1, mw2, mb2, out);
}